// Round 5
// baseline (163.001 us; speedup 1.0000x reference)
//
#include <hip/hip_runtime.h>

// CfC cell, fp16-MFMA implementation.
//   h   = 1.7159*tanh(0.666*(concat(input,hx) @ Wb^T + bb))   [B,1024]
//   ff1 = tanh(h@W1^T+b1), ff2 = tanh(h@W2^T+b2)
//   t   = sigmoid((h@Wa^T+ba)*ts + (h@Wt^T+bt))
//   out = ff1 + t*(ff2-ff1)                                   [B,512]
// Round 5: gemm2 rebuilt as a DEEP pipeline: BK=32, 4 LDS buffers (128 KB),
// prefetch distance 3 (loads issued ~2 tiles before their wait -> no exposed
// VMEM latency), 2 phases/tile, 3 barriers/tile, counted vmcnt(8/4/0) tail.
// Fragment indexing + chunk-XOR swizzle identical to the verified round-3/4
// scheme. gemm1 kept as round-3 pipeline.

typedef _Float16 f16;
typedef _Float16 f16x8 __attribute__((ext_vector_type(8)));
typedef _Float16 f16x4 __attribute__((ext_vector_type(4)));
typedef float f32x4 __attribute__((ext_vector_type(4)));

static constexpr int B_ = 16384, IN_ = 256, HID_ = 512, UNITS_ = 1024, CAT_ = 768;

__device__ __forceinline__ void gload_lds16(const void* g, void* l) {
  __builtin_amdgcn_global_load_lds(
      (const __attribute__((address_space(1))) void*)g,
      (__attribute__((address_space(3))) void*)l, 16, 0, 0);
}

// ---- conversion kernels -------------------------------------------------

__global__ void build_x_kernel(const float* __restrict__ inp,
                               const float* __restrict__ hx,
                               f16* __restrict__ x) {
  const int per_row = CAT_ / 4;
  int gid = blockIdx.x * blockDim.x + threadIdx.x;
  if (gid >= B_ * per_row) return;
  int b = gid / per_row, j = gid - b * per_row;
  float4 v;
  if (j < IN_ / 4) v = ((const float4*)(inp + (size_t)b * IN_))[j];
  else             v = ((const float4*)(hx  + (size_t)b * HID_))[j - IN_ / 4];
  f16x4 o = {(f16)v.x, (f16)v.y, (f16)v.z, (f16)v.w};
  *((f16x4*)(x + (size_t)b * CAT_ + j * 4)) = o;
}

__global__ void cvt_all_kernel(const float* __restrict__ Wb,
                               const float* __restrict__ W1,
                               const float* __restrict__ W2,
                               const float* __restrict__ Wa,
                               const float* __restrict__ Wt,
                               f16* __restrict__ dWb, f16* __restrict__ dWh) {
  const int seg = blockIdx.y;
  const int i = blockIdx.x * blockDim.x + threadIdx.x;
  const float* s;
  f16* d;
  int n4;
  if (seg == 0) {
    s = Wb; d = dWb; n4 = UNITS_ * CAT_ / 4;
  } else {
    const float* srcs[4] = {W1, W2, Wa, Wt};
    s = srcs[seg - 1];
    d = dWh + (size_t)(seg - 1) * HID_ * UNITS_;
    n4 = HID_ * UNITS_ / 4;
  }
  if (i >= n4) return;
  float4 v = ((const float4*)s)[i];
  f16x4 o = {(f16)v.x, (f16)v.y, (f16)v.z, (f16)v.w};
  ((f16x4*)d)[i] = o;
}

// ---- GEMM1: h = lecun_tanh(X @ Wb^T + bb) ------------------------------
// Round-3 structure (3-buffer counted-vmcnt, 64B-row chunk swizzle). Kept.

__global__ __launch_bounds__(256) void gemm1_kernel(
    const f16* __restrict__ X, const f16* __restrict__ Wb,
    const float* __restrict__ bb, f16* __restrict__ H) {
  constexpr int BM = 128, BN = 128, BK = 32, K = CAT_, N = UNITS_;
  constexpr int NT = K / BK;  // 24
  __shared__ f16 As[3][BM * BK];
  __shared__ f16 Bs[3][BN * BK];
  const int t = threadIdx.x;
  const int lane = t & 63, wid = t >> 6;
  const int wr = wid >> 1, wc = wid & 1;
  const int wg = (blockIdx.x & 7) * 128 + (blockIdx.x >> 3);
  const int bc = wg & 7;
  const int br = wg >> 3;
  const size_t arow0 = (size_t)br * BM;
  const size_t brow0 = (size_t)bc * BN;

  f32x4 acc[4][4] = {};

  const int srow = t >> 2;
  const int schunk = ((t & 3) ^ ((t >> 3) & 3)) * 8;
  const f16* aptr0 = X + (arow0 + srow) * K + schunk;
  const f16* aptr1 = X + (arow0 + 64 + srow) * K + schunk;
  const f16* bptr0 = Wb + (brow0 + srow) * K + schunk;
  const f16* bptr1 = Wb + (brow0 + 64 + srow) * K + schunk;
  const int l8 = t * 8;
  const int fr = lane & 15;
  const int ksw = ((lane >> 4) ^ ((lane >> 1) & 3)) * 8;

  auto stage = [&](int buf, int k0) {
    gload_lds16(aptr0 + k0, &As[buf][l8]);
    gload_lds16(aptr1 + k0, &As[buf][64 * BK + l8]);
    gload_lds16(bptr0 + k0, &Bs[buf][l8]);
    gload_lds16(bptr1 + k0, &Bs[buf][64 * BK + l8]);
  };

  stage(0, 0);
  stage(1, BK);
  asm volatile("s_waitcnt vmcnt(4)" ::: "memory");
  __builtin_amdgcn_s_barrier();
  asm volatile("" ::: "memory");

  for (int tt = 0; tt < NT; ++tt) {
    const int cur = tt % 3;
    if (tt + 2 < NT) stage((tt + 2) % 3, (tt + 2) * BK);
    f16x8 af[4], bf[4];
#pragma unroll
    for (int m = 0; m < 4; ++m)
      af[m] = *((const f16x8*)(&As[cur][(wr * 64 + m * 16 + fr) * BK + ksw]));
#pragma unroll
    for (int n = 0; n < 4; ++n)
      bf[n] = *((const f16x8*)(&Bs[cur][(wc * 64 + n * 16 + fr) * BK + ksw]));
#pragma unroll
    for (int m = 0; m < 4; ++m)
#pragma unroll
      for (int n = 0; n < 4; ++n)
        acc[m][n] = __builtin_amdgcn_mfma_f32_16x16x32_f16(af[m], bf[n], acc[m][n], 0, 0, 0);
    if (tt + 2 < NT) asm volatile("s_waitcnt vmcnt(4)" ::: "memory");
    else             asm volatile("s_waitcnt vmcnt(0)" ::: "memory");
    __builtin_amdgcn_s_barrier();
    asm volatile("" ::: "memory");
  }

#pragma unroll
  for (int m = 0; m < 4; ++m) {
#pragma unroll
    for (int n = 0; n < 4; ++n) {
      const int colg = (int)brow0 + wc * 64 + n * 16 + (lane & 15);
      const float bias = bb[colg];
#pragma unroll
      for (int i = 0; i < 4; ++i) {
        const int rowg = (int)arow0 + wr * 64 + m * 16 + (lane >> 4) * 4 + i;
        float v = acc[m][n][i] + bias;
        v = 1.7159f * tanhf(0.666f * v);
        H[(size_t)rowg * N + colg] = (f16)v;
      }
    }
  }
}

// ---- GEMM2: four heads fused, deep 4-buffer pipeline --------------------
// Block: 512 thr / 8 waves (wr 0..1 x wc 0..3). Tile 256 rows x 256 col-
// entities (4 heads x 64 HID-cols). BK=32, NT=32, 4 LDS buffers (128 KB),
// prefetch distance 3: tile t+3 staged during tile t, awaited ~2 tiles
// later -> no exposed VMEM latency. 2 phases/tile (16 MFMA each).
// B-LDS rows: [head][64 cols]; A-LDS rows: 256 block rows. Chunk-XOR
// swizzle: phys 16B-chunk = logical ^ (row&3), both-sides involution.

__global__ __launch_bounds__(512, 2) void gemm2_kernel(
    const f16* __restrict__ H, const f16* __restrict__ W,
    const float* __restrict__ b1, const float* __restrict__ b2,
    const float* __restrict__ ba, const float* __restrict__ bt,
    const float* __restrict__ ts, float* __restrict__ out) {
  constexpr int BK = 32, K = UNITS_;
  constexpr int NT = K / BK;  // 32
  __shared__ f16 As[4][256 * BK];  // 64 KB
  __shared__ f16 Bs[4][256 * BK];  // 64 KB
  const int t = threadIdx.x;
  const int lane = t & 63, wid = t >> 6;
  const int wr = wid >> 2;      // 0..1
  const int wc = wid & 3;       // 0..3
  const int wg = (blockIdx.x & 7) * 64 + (blockIdx.x >> 3);  // XCD swizzle
  const int bc = wg & 7;        // 8 col-blocks of 64 HID cols
  const int br = wg >> 3;       // 64 row-blocks
  const int arow0 = br * 256;
  const int bcol0 = bc * 64;

  f32x4 acc[8][4] = {};  // [m over 128 rows][head]

  // staging: per 8KB call, thread t covers row r0 = t>>2, phys chunk t&3.
  const int r0 = t >> 2;                          // 0..127
  const int schunk = ((t & 3) ^ (r0 & 3)) * 8;    // pre-swizzled source chunk
  const f16* aP[2];
  aP[0] = H + (size_t)(arow0 + r0) * K + schunk;        // A rows 0..127
  aP[1] = H + (size_t)(arow0 + 128 + r0) * K + schunk;  // A rows 128..255
  const f16* bP[2];
  // B-LDS row p*128 + r0 = head*64 + col; head = p*2 + (r0>>6), col = r0&63
  bP[0] = W + (size_t)(((r0 >> 6)) * 512 + bcol0 + (r0 & 63)) * K + schunk;
  bP[1] = W + (size_t)((2 + (r0 >> 6)) * 512 + bcol0 + (r0 & 63)) * K + schunk;
  const int l16 = t * 8;  // f16 offset within an 8KB (128-row) half

  const int fr = lane & 15;
  const int klo = lane >> 4;                 // 0..3
  const int kx = (klo ^ (fr & 3)) * 8;       // swizzled read chunk (f16)

#define STAGE_A(buf, p, k0) gload_lds16(aP[p] + (k0), &As[buf][(p) * 4096 + l16])
#define STAGE_B(buf, p, k0) gload_lds16(bP[p] + (k0), &Bs[buf][(p) * 4096 + l16])
#define BARRIER() do { asm volatile("" ::: "memory"); __builtin_amdgcn_s_barrier(); asm volatile("" ::: "memory"); } while (0)

  // prologue: tiles 0,1,2 in flight (12 loads); wait tile 0 (8 newer remain)
#pragma unroll
  for (int q = 0; q < 3; ++q) {
    STAGE_A(q, 0, q * BK); STAGE_A(q, 1, q * BK);
    STAGE_B(q, 0, q * BK); STAGE_B(q, 1, q * BK);
  }
  asm volatile("s_waitcnt vmcnt(8)" ::: "memory");
  __builtin_amdgcn_s_barrier();
  asm volatile("" ::: "memory");

  for (int tt = 0; tt < NT; ++tt) {
    const int cur = tt & 3;
    const int nb = (tt + 3) & 3;
    const int k3 = (tt + 3) * BK;
    const bool st = (tt + 3 < NT);

    f16x8 aF[4], bF[4];
    // ---- P1: read A m0..3 + all B; stage A(t+3) ----
#pragma unroll
    for (int m = 0; m < 4; ++m)
      aF[m] = *((const f16x8*)(&As[cur][(wr * 128 + m * 16 + fr) * BK + kx]));
#pragma unroll
    for (int h = 0; h < 4; ++h)
      bF[h] = *((const f16x8*)(&Bs[cur][(h * 64 + wc * 16 + fr) * BK + kx]));
    if (st) { STAGE_A(nb, 0, k3); STAGE_A(nb, 1, k3); }
    BARRIER();
    __builtin_amdgcn_s_setprio(1);
#pragma unroll
    for (int m = 0; m < 4; ++m)
#pragma unroll
      for (int h = 0; h < 4; ++h)
        acc[m][h] = __builtin_amdgcn_mfma_f32_16x16x32_f16(aF[m], bF[h], acc[m][h], 0, 0, 0);
    __builtin_amdgcn_s_setprio(0);

    // ---- P2: read A m4..7; stage B(t+3) ----
    f16x8 aG[4];
#pragma unroll
    for (int m = 0; m < 4; ++m)
      aG[m] = *((const f16x8*)(&As[cur][(wr * 128 + 64 + m * 16 + fr) * BK + kx]));
    if (st) { STAGE_B(nb, 0, k3); STAGE_B(nb, 1, k3); }
    BARRIER();
    __builtin_amdgcn_s_setprio(1);
#pragma unroll
    for (int m = 0; m < 4; ++m)
#pragma unroll
      for (int h = 0; h < 4; ++h)
        acc[4 + m][h] = __builtin_amdgcn_mfma_f32_16x16x32_f16(aG[m], bF[h], acc[4 + m][h], 0, 0, 0);
    __builtin_amdgcn_s_setprio(0);

    // end-of-tile: ensure tile tt+1 fully landed before next iteration.
    if (tt + 3 < NT)      asm volatile("s_waitcnt vmcnt(8)" ::: "memory");
    else if (tt + 2 < NT) asm volatile("s_waitcnt vmcnt(4)" ::: "memory");
    else if (tt + 1 < NT) asm volatile("s_waitcnt vmcnt(0)" ::: "memory");
    BARRIER();
  }
#undef STAGE_A
#undef STAGE_B
#undef BARRIER

  // epilogue: wave covers rows wr*128 + m*16 + klo*4 + i, col bcol0+wc*16+fr
  const int colg = bcol0 + wc * 16 + fr;
  const float B1 = b1[colg], B2 = b2[colg], BA = ba[colg], BT = bt[colg];
#pragma unroll
  for (int m = 0; m < 8; ++m) {
#pragma unroll
    for (int i = 0; i < 4; ++i) {
      const int rowg = arow0 + wr * 128 + m * 16 + klo * 4 + i;
      const float ff1 = tanhf(acc[m][0][i] + B1);
      const float ff2 = tanhf(acc[m][1][i] + B2);
      const float ta = acc[m][2][i] + BA;
      const float tb = acc[m][3][i] + BT;
      const float z = ta * ts[rowg] + tb;
      const float ti = 1.0f / (1.0f + __expf(-z));
      out[(size_t)rowg * HID_ + colg] = ff1 + ti * (ff2 - ff1);
    }
  }
}

// ---- launch -------------------------------------------------------------

extern "C" void kernel_launch(void* const* d_in, const int* in_sizes, int n_in,
                              void* d_out, int out_size, void* d_ws, size_t ws_size,
                              hipStream_t stream) {
  const float* input = (const float*)d_in[0];
  const float* hx    = (const float*)d_in[1];
  const float* ts    = (const float*)d_in[2];
  const float* Wb    = (const float*)d_in[3];
  const float* bb    = (const float*)d_in[4];
  const float* W1    = (const float*)d_in[5];
  const float* b1    = (const float*)d_in[6];
  const float* W2    = (const float*)d_in[7];
  const float* b2    = (const float*)d_in[8];
  const float* Wa    = (const float*)d_in[9];
  const float* ba    = (const float*)d_in[10];
  const float* Wt    = (const float*)d_in[11];
  const float* bt    = (const float*)d_in[12];
  float* out = (float*)d_out;

  char* ws = (char*)d_ws;
  f16* x_f16  = (f16*)ws;  ws += (size_t)B_ * CAT_ * 2;
  f16* h_f16  = (f16*)ws;  ws += (size_t)B_ * UNITS_ * 2;
  f16* Wb_f16 = (f16*)ws;  ws += (size_t)UNITS_ * CAT_ * 2;
  f16* Wh_f16 = (f16*)ws;  ws += (size_t)4 * HID_ * UNITS_ * 2;

  build_x_kernel<<<(B_ * (CAT_ / 4) + 255) / 256, 256, 0, stream>>>(input, hx, x_f16);
  cvt_all_kernel<<<dim3((UNITS_ * CAT_ / 4 + 255) / 256, 5), 256, 0, stream>>>(
      Wb, W1, W2, Wa, Wt, Wb_f16, Wh_f16);

  gemm1_kernel<<<dim3(128 * 8), 256, 0, stream>>>(x_f16, Wb_f16, bb, h_f16);
  gemm2_kernel<<<dim3(64 * 8), 512, 0, stream>>>(h_f16, Wh_f16, b1, b2, ba, bt, ts, out);
}